// Round 10
// baseline (156.588 us; speedup 1.0000x reference)
//
#include <hip/hip_runtime.h>
#include <hip/hip_bf16.h>

#define NN    50000
#define EE    1600000
#define IND   128
#define OUTD  64
#define SLOPE 0.1f

// fine buckets (aggregate granularity): fine b = coarse(b>>3), sub(b&7)
#define BSH    5                   // log2(nodes per fine bucket)
#define BW     32                  // nodes per fine bucket
#define NB     1564                // ceil(NN / 32) aggregate blocks
#define CAP    1408                // fine capacity: mean 1024 + 12 sigma
// coarse buckets
#define CSH    8                   // log2(nodes per coarse bucket)
#define NC     196                 // ceil(NN / 256)
#define CAP1   8832                // coarse capacity: mean 8192 + 7 sigma
#define NBLK1  500
#define CHUNK1 (EE / NBLK1)        // 3200 edges per coarse block
#define NLIN   (NN / 16)           // 3125 linear blocks

typedef __attribute__((ext_vector_type(8))) short short8;
typedef __attribute__((ext_vector_type(4))) float float4v;

// ---------------------------------------------------------------------------
// Fused K1: blocks [0,NBLK1) = coarse bin; blocks [NBLK1, NBLK1+NLIN) = MFMA
// linear. Independent workloads on different pipes (VMEM-atomic vs MFMA).
// Barriers are block-uniform (branch on blockIdx only).
// ---------------------------------------------------------------------------
union SMem {
    struct {
        ushort xs[16 * 136];        // x tile bf16 (pad 8/row)
        ushort wt[64 * 136];        // W bf16
        float  newt[16 * 68];       // fp32 out tile (pad 4)
    } lin;
    int h[NC];                      // coarse histogram/cursors
};

__global__ __launch_bounds__(256) void fused_lincoarse_kernel(
    const float* __restrict__ x, const float* __restrict__ W,
    const float* __restrict__ bias, const float* __restrict__ a,
    const int* __restrict__ ei, int* __restrict__ gcur1,
    unsigned* __restrict__ ebuf1,
    ushort* __restrict__ nbuf2, float* __restrict__ s_src, float* __restrict__ s_dst)
{
    __shared__ SMem sm;
    const int tid = threadIdx.x;

    if (blockIdx.x < NBLK1) {
        // ----- coarse bin: 196 buckets of 256 nodes; runs ~16 = full lines
        int* h = sm.h;
        for (int i = tid; i < NC; i += 256) h[i] = 0;
        __syncthreads();
        const int base = blockIdx.x * CHUNK1;
        const int4* s4p = (const int4*)(ei + base);
        for (int i = tid; i < CHUNK1 / 4; i += 256) {
            int4 s4 = s4p[i];
            atomicAdd(&h[s4.x >> CSH], 1);
            atomicAdd(&h[s4.y >> CSH], 1);
            atomicAdd(&h[s4.z >> CSH], 1);
            atomicAdd(&h[s4.w >> CSH], 1);
        }
        __syncthreads();
        for (int i = tid; i < NC; i += 256) {
            int c = h[i];
            if (c) h[i] = i * CAP1 + atomicAdd(&gcur1[i * 16], c);
        }
        __syncthreads();
        const int4* d4p = (const int4*)(ei + EE + base);
        for (int i = tid; i < CHUNK1 / 4; i += 256) {
            int4 s4 = s4p[i];
            int4 d4 = d4p[i];
            int p0 = atomicAdd(&h[s4.x >> CSH], 1);
            int p1 = atomicAdd(&h[s4.y >> CSH], 1);
            int p2 = atomicAdd(&h[s4.z >> CSH], 1);
            int p3 = atomicAdd(&h[s4.w >> CSH], 1);
            ebuf1[p0] = ((unsigned)(s4.x & 255) << 16) | (unsigned)d4.x;
            ebuf1[p1] = ((unsigned)(s4.y & 255) << 16) | (unsigned)d4.y;
            ebuf1[p2] = ((unsigned)(s4.z & 255) << 16) | (unsigned)d4.z;
            ebuf1[p3] = ((unsigned)(s4.w & 255) << 16) | (unsigned)d4.w;
        }
        return;
    }

    // ----- MFMA linear: new = x@W.T + b, bf16 out + fused score dots
    const int node0 = (blockIdx.x - NBLK1) * 16;
    const float4* W4 = (const float4*)W;
    #pragma unroll
    for (int i = 0; i < 8; ++i) {
        int idx = tid + i * 256;
        float4 wv = W4[idx];
        int n = idx >> 5, k = (idx & 31) * 4;
        ushort4 pk; __hip_bfloat16 h;
        h = __float2bfloat16(wv.x); pk.x = *(ushort*)&h;
        h = __float2bfloat16(wv.y); pk.y = *(ushort*)&h;
        h = __float2bfloat16(wv.z); pk.z = *(ushort*)&h;
        h = __float2bfloat16(wv.w); pk.w = *(ushort*)&h;
        *(ushort4*)&sm.lin.wt[n * 136 + k] = pk;
    }
    const float4* x4 = (const float4*)(x + (size_t)node0 * IND);
    #pragma unroll
    for (int i = 0; i < 2; ++i) {
        int idx = tid + i * 256;
        float4 xv = x4[idx];
        int r = idx >> 5, cc = (idx & 31) * 4;
        ushort4 pk; __hip_bfloat16 h;
        h = __float2bfloat16(xv.x); pk.x = *(ushort*)&h;
        h = __float2bfloat16(xv.y); pk.y = *(ushort*)&h;
        h = __float2bfloat16(xv.z); pk.z = *(ushort*)&h;
        h = __float2bfloat16(xv.w); pk.w = *(ushort*)&h;
        *(ushort4*)&sm.lin.xs[r * 136 + cc] = pk;
    }
    __syncthreads();

    const int w    = tid >> 6;
    const int lane = tid & 63;
    const int q    = lane >> 4;
    const int m16  = lane & 15;
    float4v acc = {0.f, 0.f, 0.f, 0.f};
    #pragma unroll
    for (int kk = 0; kk < IND; kk += 32) {
        short8 af = *(const short8*)&sm.lin.xs[m16 * 136 + kk + q * 8];
        short8 bf = *(const short8*)&sm.lin.wt[(w * 16 + m16) * 136 + kk + q * 8];
        acc = __builtin_amdgcn_mfma_f32_16x16x32_bf16(af, bf, acc, 0, 0, 0);
    }
    const float bv = bias[w * 16 + m16];
    #pragma unroll
    for (int r = 0; r < 4; ++r)         // D: col=lane&15, row=quad*4+r
        sm.lin.newt[(q * 4 + r) * 68 + w * 16 + m16] = acc[r] + bv;
    __syncthreads();

    const int nl = tid >> 4;
    const int jg = tid & 15;
    const int j0 = jg * 4;
    float4 va = *(const float4*)&sm.lin.newt[nl * 68 + j0];
    const int n = node0 + nl;
    ushort4 pk;
    { __hip_bfloat16 h;
      h = __float2bfloat16(va.x); pk.x = *(ushort*)&h;
      h = __float2bfloat16(va.y); pk.y = *(ushort*)&h;
      h = __float2bfloat16(va.z); pk.z = *(ushort*)&h;
      h = __float2bfloat16(va.w); pk.w = *(ushort*)&h; }
    *(ushort4*)&nbuf2[(size_t)n * OUTD + j0] = pk;

    float ss = va.x * a[j0]        + va.y * a[j0 + 1]
             + va.z * a[j0 + 2]    + va.w * a[j0 + 3];
    float sd = va.x * a[OUTD + j0]     + va.y * a[OUTD + j0 + 1]
             + va.z * a[OUTD + j0 + 2] + va.w * a[OUTD + j0 + 3];
    #pragma unroll
    for (int m = 1; m < 16; m <<= 1) {
        ss += __shfl_xor(ss, m, 64);
        sd += __shfl_xor(sd, m, 64);
    }
    if (jg == 0) { s_src[n] = ss; s_dst[n] = sd; }
}

// ---------------------------------------------------------------------------
// Fused aggregate v6: one block per 32-node fine bucket, reading the parent
// coarse bucket DIRECTLY (finebin stage deleted). Block b: coarse c=b>>3,
// sub f=b&7; edges filtered by bits 21..23 of the packed word. Two passes
// (count, then exp+scatter) — no register stash, L2-hot re-read (~35KB).
// Phase D: 4 edges per wave instruction — quarter-wave e16=lane>>4 handles
// edge j+e16; lane c16=lane&15 gathers uint2 = 4 bf16 dims (128B/row).
// ---------------------------------------------------------------------------
__global__ __launch_bounds__(256) void aggregate_kernel(
    const unsigned* __restrict__ ebuf1, const int* __restrict__ gcur1,
    const ushort* __restrict__ nbuf2,
    const float* __restrict__ s_src, const float* __restrict__ s_dst,
    float* __restrict__ out)
{
    __shared__ uint2 pairs[CAP];        // {d, bits(ev)} sorted by node
    __shared__ float ssL[BW];
    __shared__ int cntL[BW], ofs[BW], cur[BW];
    const int tid  = threadIdx.x;
    const int wid  = tid >> 6;
    const int lane = tid & 63;
    const int b    = blockIdx.x;
    const int c    = b >> 3;                      // parent coarse bucket
    const unsigned fsub = (unsigned)(b & 7);      // sub id = bits 21..23
    const int n0   = b << BSH;
    const uint2* __restrict__ nbufq = (const uint2*)nbuf2;  // row = 16 uint2

    if (tid < BW) {
        int n = n0 + tid;
        ssL[tid]  = (n < NN) ? s_src[n] : 0.f;
        cntL[tid] = 0;
    }
    __syncthreads();

    const int cnt1 = gcur1[c * 16];
    const unsigned* eb = ebuf1 + (size_t)c * CAP1;

    // pass 1: per-node histogram of my sub-bucket's edges (uint4 filter)
    const int nv = cnt1 >> 2;
    const uint4* eb4 = (const uint4*)eb;
    for (int i = tid; i < nv; i += 256) {
        uint4 e4 = eb4[i];
        if ((e4.x >> 21) == fsub) atomicAdd(&cntL[(e4.x >> 16) & 31], 1);
        if ((e4.y >> 21) == fsub) atomicAdd(&cntL[(e4.y >> 16) & 31], 1);
        if ((e4.z >> 21) == fsub) atomicAdd(&cntL[(e4.z >> 16) & 31], 1);
        if ((e4.w >> 21) == fsub) atomicAdd(&cntL[(e4.w >> 16) & 31], 1);
    }
    for (int i = (nv << 2) + tid; i < cnt1; i += 256) {
        unsigned e = eb[i];
        if ((e >> 21) == fsub) atomicAdd(&cntL[(e >> 16) & 31], 1);
    }
    __syncthreads();

    if (wid == 0) {                               // 32-ctr exclusive scan
        int cc = (lane < BW) ? cntL[lane] : 0;
        int sc = cc;
        #pragma unroll
        for (int m = 1; m < BW; m <<= 1) {
            int v = __shfl_up(sc, m, 64);
            if (lane >= m) sc += v;
        }
        if (lane < BW) { ofs[lane] = sc - cc; cur[lane] = sc - cc; }
    }
    __syncthreads();

    // pass 2: recompute score+exp, scatter sorted by node (L2-hot re-read)
    for (int i = tid; i < cnt1; i += 256) {
        unsigned e = eb[i];
        if ((e >> 21) != fsub) continue;
        int d  = e & 0xFFFFu;
        int ln = (e >> 16) & 31;
        float sc = ssL[ln] + s_dst[d];
        float lr = sc > 0.f ? sc : SLOPE * sc;
        float ev = __expf(lr);
        int pos = atomicAdd(&cur[ln], 1);
        pairs[pos] = make_uint2((unsigned)d, __float_as_uint(ev));
    }
    __syncthreads();

    const int e16 = lane >> 4;                    // quarter: edge offset
    const int c16 = lane & 15;                    // 4-dim group (uint2)

    #pragma unroll 1
    for (int t = 0; t < BW / 4; ++t) {            // wave's 8 nodes
        const int ln  = wid * (BW / 4) + t;
        const int beg = ofs[ln];
        const int len = cntL[ln];

        float a0 = 0.f, a1 = 0.f, a2 = 0.f, a3 = 0.f, es = 0.f;
        int j = 0;
        for (; j + 16 <= len; j += 16) {          // 16 edges: 4 per quarter
            uint2 pA = pairs[beg + j + 0  + e16];
            uint2 pB = pairs[beg + j + 4  + e16];
            uint2 pC = pairs[beg + j + 8  + e16];
            uint2 pD = pairs[beg + j + 12 + e16];
            uint2 gA = nbufq[pA.x * 16 + c16];
            uint2 gB = nbufq[pB.x * 16 + c16];
            uint2 gC = nbufq[pC.x * 16 + c16];
            uint2 gD = nbufq[pD.x * 16 + c16];
            float fA = __uint_as_float(pA.y), fB = __uint_as_float(pB.y);
            float fC = __uint_as_float(pC.y), fD = __uint_as_float(pD.y);
            es += fA + fB + fC + fD;
            a0 = fmaf(fA, __uint_as_float(gA.x << 16), a0);
            a1 = fmaf(fA, __uint_as_float(gA.x & 0xFFFF0000u), a1);
            a2 = fmaf(fA, __uint_as_float(gA.y << 16), a2);
            a3 = fmaf(fA, __uint_as_float(gA.y & 0xFFFF0000u), a3);
            a0 = fmaf(fB, __uint_as_float(gB.x << 16), a0);
            a1 = fmaf(fB, __uint_as_float(gB.x & 0xFFFF0000u), a1);
            a2 = fmaf(fB, __uint_as_float(gB.y << 16), a2);
            a3 = fmaf(fB, __uint_as_float(gB.y & 0xFFFF0000u), a3);
            a0 = fmaf(fC, __uint_as_float(gC.x << 16), a0);
            a1 = fmaf(fC, __uint_as_float(gC.x & 0xFFFF0000u), a1);
            a2 = fmaf(fC, __uint_as_float(gC.y << 16), a2);
            a3 = fmaf(fC, __uint_as_float(gC.y & 0xFFFF0000u), a3);
            a0 = fmaf(fD, __uint_as_float(gD.x << 16), a0);
            a1 = fmaf(fD, __uint_as_float(gD.x & 0xFFFF0000u), a1);
            a2 = fmaf(fD, __uint_as_float(gD.y << 16), a2);
            a3 = fmaf(fD, __uint_as_float(gD.y & 0xFFFF0000u), a3);
        }
        for (; j < len; j += 4) {                 // tail: clamp + mask
            int idx = j + e16;
            uint2 p = pairs[beg + min(idx, len - 1)];
            float f = (idx < len) ? __uint_as_float(p.y) : 0.f;
            uint2 g = nbufq[p.x * 16 + c16];
            es += f;
            a0 = fmaf(f, __uint_as_float(g.x << 16), a0);
            a1 = fmaf(f, __uint_as_float(g.x & 0xFFFF0000u), a1);
            a2 = fmaf(f, __uint_as_float(g.y << 16), a2);
            a3 = fmaf(f, __uint_as_float(g.y & 0xFFFF0000u), a3);
        }
        es += __shfl_xor(es, 16, 64); es += __shfl_xor(es, 32, 64);
        a0 += __shfl_xor(a0, 16, 64); a0 += __shfl_xor(a0, 32, 64);
        a1 += __shfl_xor(a1, 16, 64); a1 += __shfl_xor(a1, 32, 64);
        a2 += __shfl_xor(a2, 16, 64); a2 += __shfl_xor(a2, 32, 64);
        a3 += __shfl_xor(a3, 16, 64); a3 += __shfl_xor(a3, 32, 64);
        const int n = n0 + ln;
        if (e16 == 0 && n < NN) {
            float inv = 1.f / (es + 1e-12f);
            float4 o = make_float4(a0 * inv, a1 * inv, a2 * inv, a3 * inv);
            *(float4*)&out[(size_t)n * OUTD + c16 * 4] = o;
        }
    }
}

// ---------------------------------------------------------------------------
extern "C" void kernel_launch(void* const* d_in, const int* in_sizes, int n_in,
                              void* d_out, int out_size, void* d_ws, size_t ws_size,
                              hipStream_t stream) {
    const float* x  = (const float*)d_in[0];
    const int*   ei = (const int*)d_in[1];    // (2,E): [0..E)=src, [E..2E)=dst
    const float* W  = (const float*)d_in[2];
    const float* b  = (const float*)d_in[3];
    const float* a  = (const float*)d_in[4];
    float* out = (float*)d_out;

    // workspace layout (~14 MB)
    ushort*   nbuf2 = (ushort*)d_ws;                      // N*64 bf16 = 6.4 MB
    float*    s_src = (float*)(nbuf2 + (size_t)NN * OUTD);// N
    float*    s_dst = s_src + NN;                         // N
    int*      gcur1 = (int*)(s_dst + NN);                 // NC*16
    unsigned* ebuf1 = (unsigned*)(gcur1 + NC * 16);       // NC*CAP1 = 6.9 MB

    hipMemsetAsync(gcur1, 0, NC * 16 * sizeof(int), stream);
    fused_lincoarse_kernel<<<NBLK1 + NLIN, 256, 0, stream>>>(
        x, W, b, a, ei, gcur1, ebuf1, nbuf2, s_src, s_dst);
    aggregate_kernel<<<NB, 256, 0, stream>>>(ebuf1, gcur1, nbuf2, s_src, s_dst, out);
}

// Round 11
// 152.832 us; speedup vs baseline: 1.0246x; 1.0246x over previous
//
#include <hip/hip_runtime.h>
#include <hip/hip_bf16.h>

#define NN    50000
#define EE    1600000
#define IND   128
#define OUTD  64
#define SLOPE 0.1f

// coarse buckets
#define CSH    8                   // log2(nodes per coarse bucket)
#define NC     196                 // ceil(NN / 256)
#define CAP1   8832                // coarse capacity: mean 8192 + 7 sigma
#define NBLK1  500
#define CHUNK1 (EE / NBLK1)        // 3200 edges per coarse block
#define NLIN   (NN / 16)           // 3125 linear blocks
// aggregate: one block per coarse-bucket HALF (128 nodes)
#define NAGG   (NC * 2)            // 392 blocks x 512 threads
#define HCAP   5120                // half-bucket bound: mean 4416 + 15 sigma
#define STASH  18                  // ceil(CAP1 / 512) register stash bound

typedef __attribute__((ext_vector_type(8))) short short8;
typedef __attribute__((ext_vector_type(4))) float float4v;

// ---------------------------------------------------------------------------
// Fused K1: blocks [0,NBLK1) = coarse bin; blocks [NBLK1, NBLK1+NLIN) = MFMA
// linear. Independent workloads on different pipes (VMEM-atomic vs MFMA).
// Barriers are block-uniform (branch on blockIdx only).
// ---------------------------------------------------------------------------
union SMem {
    struct {
        ushort xs[16 * 136];        // x tile bf16 (pad 8/row)
        ushort wt[64 * 136];        // W bf16
        float  newt[16 * 68];       // fp32 out tile (pad 4)
    } lin;
    int h[NC];                      // coarse histogram/cursors
};

__global__ __launch_bounds__(256) void fused_lincoarse_kernel(
    const float* __restrict__ x, const float* __restrict__ W,
    const float* __restrict__ bias, const float* __restrict__ a,
    const int* __restrict__ ei, int* __restrict__ gcur1,
    unsigned* __restrict__ ebuf1,
    ushort* __restrict__ nbuf2, float* __restrict__ s_src, float* __restrict__ s_dst)
{
    __shared__ SMem sm;
    const int tid = threadIdx.x;

    if (blockIdx.x < NBLK1) {
        // ----- coarse bin: 196 buckets of 256 nodes; runs ~16 = full lines
        int* h = sm.h;
        for (int i = tid; i < NC; i += 256) h[i] = 0;
        __syncthreads();
        const int base = blockIdx.x * CHUNK1;
        const int4* s4p = (const int4*)(ei + base);
        for (int i = tid; i < CHUNK1 / 4; i += 256) {
            int4 s4 = s4p[i];
            atomicAdd(&h[s4.x >> CSH], 1);
            atomicAdd(&h[s4.y >> CSH], 1);
            atomicAdd(&h[s4.z >> CSH], 1);
            atomicAdd(&h[s4.w >> CSH], 1);
        }
        __syncthreads();
        for (int i = tid; i < NC; i += 256) {
            int c = h[i];
            if (c) h[i] = i * CAP1 + atomicAdd(&gcur1[i * 16], c);
        }
        __syncthreads();
        const int4* d4p = (const int4*)(ei + EE + base);
        for (int i = tid; i < CHUNK1 / 4; i += 256) {
            int4 s4 = s4p[i];
            int4 d4 = d4p[i];
            int p0 = atomicAdd(&h[s4.x >> CSH], 1);
            int p1 = atomicAdd(&h[s4.y >> CSH], 1);
            int p2 = atomicAdd(&h[s4.z >> CSH], 1);
            int p3 = atomicAdd(&h[s4.w >> CSH], 1);
            ebuf1[p0] = ((unsigned)(s4.x & 255) << 16) | (unsigned)d4.x;
            ebuf1[p1] = ((unsigned)(s4.y & 255) << 16) | (unsigned)d4.y;
            ebuf1[p2] = ((unsigned)(s4.z & 255) << 16) | (unsigned)d4.z;
            ebuf1[p3] = ((unsigned)(s4.w & 255) << 16) | (unsigned)d4.w;
        }
        return;
    }

    // ----- MFMA linear: new = x@W.T + b, bf16 out + fused score dots
    const int node0 = (blockIdx.x - NBLK1) * 16;
    const float4* W4 = (const float4*)W;
    #pragma unroll
    for (int i = 0; i < 8; ++i) {
        int idx = tid + i * 256;
        float4 wv = W4[idx];
        int n = idx >> 5, k = (idx & 31) * 4;
        ushort4 pk; __hip_bfloat16 h;
        h = __float2bfloat16(wv.x); pk.x = *(ushort*)&h;
        h = __float2bfloat16(wv.y); pk.y = *(ushort*)&h;
        h = __float2bfloat16(wv.z); pk.z = *(ushort*)&h;
        h = __float2bfloat16(wv.w); pk.w = *(ushort*)&h;
        *(ushort4*)&sm.lin.wt[n * 136 + k] = pk;
    }
    const float4* x4 = (const float4*)(x + (size_t)node0 * IND);
    #pragma unroll
    for (int i = 0; i < 2; ++i) {
        int idx = tid + i * 256;
        float4 xv = x4[idx];
        int r = idx >> 5, cc = (idx & 31) * 4;
        ushort4 pk; __hip_bfloat16 h;
        h = __float2bfloat16(xv.x); pk.x = *(ushort*)&h;
        h = __float2bfloat16(xv.y); pk.y = *(ushort*)&h;
        h = __float2bfloat16(xv.z); pk.z = *(ushort*)&h;
        h = __float2bfloat16(xv.w); pk.w = *(ushort*)&h;
        *(ushort4*)&sm.lin.xs[r * 136 + cc] = pk;
    }
    __syncthreads();

    const int w    = tid >> 6;
    const int lane = tid & 63;
    const int q    = lane >> 4;
    const int m16  = lane & 15;
    float4v acc = {0.f, 0.f, 0.f, 0.f};
    #pragma unroll
    for (int kk = 0; kk < IND; kk += 32) {
        short8 af = *(const short8*)&sm.lin.xs[m16 * 136 + kk + q * 8];
        short8 bf = *(const short8*)&sm.lin.wt[(w * 16 + m16) * 136 + kk + q * 8];
        acc = __builtin_amdgcn_mfma_f32_16x16x32_bf16(af, bf, acc, 0, 0, 0);
    }
    const float bv = bias[w * 16 + m16];
    #pragma unroll
    for (int r = 0; r < 4; ++r)         // D: col=lane&15, row=quad*4+r
        sm.lin.newt[(q * 4 + r) * 68 + w * 16 + m16] = acc[r] + bv;
    __syncthreads();

    const int nl = tid >> 4;
    const int jg = tid & 15;
    const int j0 = jg * 4;
    float4 va = *(const float4*)&sm.lin.newt[nl * 68 + j0];
    const int n = node0 + nl;
    ushort4 pk;
    { __hip_bfloat16 h;
      h = __float2bfloat16(va.x); pk.x = *(ushort*)&h;
      h = __float2bfloat16(va.y); pk.y = *(ushort*)&h;
      h = __float2bfloat16(va.z); pk.z = *(ushort*)&h;
      h = __float2bfloat16(va.w); pk.w = *(ushort*)&h; }
    *(ushort4*)&nbuf2[(size_t)n * OUTD + j0] = pk;

    float ss = va.x * a[j0]        + va.y * a[j0 + 1]
             + va.z * a[j0 + 2]    + va.w * a[j0 + 3];
    float sd = va.x * a[OUTD + j0]     + va.y * a[OUTD + j0 + 1]
             + va.z * a[OUTD + j0 + 2] + va.w * a[OUTD + j0 + 3];
    #pragma unroll
    for (int m = 1; m < 16; m <<= 1) {
        ss += __shfl_xor(ss, m, 64);
        sd += __shfl_xor(sd, m, 64);
    }
    if (jg == 0) { s_src[n] = ss; s_dst[n] = sd; }
}

// ---------------------------------------------------------------------------
// Aggregate v7: one 512-thread block per coarse-bucket HALF (392 blocks,
// 128 nodes each). The coarse bucket is read ONCE into registers (stash);
// both the filtered histogram and the exp+scatter run from the stash — no
// cross-block re-reads (R10's 16x ebuf1 refetch was the regression cause).
// Then v5's proven phase D: 4 edges per wave instruction, quarter-wave
// e16=lane>>4 handles edge j+e16; lane c16=lane&15 gathers uint2 = 4 bf16
// dims (128B/row). Quarter-combine via shfl_xor(16,32) at node end.
// ---------------------------------------------------------------------------
__global__ __launch_bounds__(512) void aggregate_kernel(
    const unsigned* __restrict__ ebuf1, const int* __restrict__ gcur1,
    const ushort* __restrict__ nbuf2,
    const float* __restrict__ s_src, const float* __restrict__ s_dst,
    float* __restrict__ out)
{
    __shared__ uint2 pairs[HCAP];       // {d, bits(ev)} sorted by node: 40 KB
    __shared__ float ssL[128];
    __shared__ int cntL[128], ofs[128], cur[128];
    const int tid  = threadIdx.x;
    const int wid  = tid >> 6;                    // 0..7
    const int lane = tid & 63;
    const int c    = blockIdx.x >> 1;             // coarse bucket
    const unsigned half = blockIdx.x & 1;         // node half (bit 7 of ln8)
    const int n0   = (c << CSH) + ((int)half << 7);
    const uint2* __restrict__ nbufq = (const uint2*)nbuf2;  // row = 16 uint2

    if (tid < 128) {
        int n = n0 + tid;
        ssL[tid]  = (n < NN) ? s_src[n] : 0.f;
        cntL[tid] = 0;
    }
    __syncthreads();

    const int cnt1 = gcur1[c * 16];
    const unsigned* eb = ebuf1 + (size_t)c * CAP1;

    // single global read: stash + filtered per-node histogram
    unsigned er[STASH];
    int nk = 0;
    for (int i = tid; i < cnt1; i += 512) {
        unsigned e = eb[i];
        er[nk++] = e;
        if ((e >> 23) == half) atomicAdd(&cntL[(e >> 16) & 127], 1);
    }
    __syncthreads();

    if (wid == 0) {                               // scan 128 ctrs, wave 0
        int c0 = cntL[lane];
        int s0 = c0;
        #pragma unroll
        for (int m = 1; m < 64; m <<= 1) {
            int v = __shfl_up(s0, m, 64);
            if (lane >= m) s0 += v;
        }
        int tot0 = __shfl(s0, 63, 64);
        ofs[lane] = s0 - c0; cur[lane] = s0 - c0;
        int c1 = cntL[64 + lane];
        int s1 = c1;
        #pragma unroll
        for (int m = 1; m < 64; m <<= 1) {
            int v = __shfl_up(s1, m, 64);
            if (lane >= m) s1 += v;
        }
        ofs[64 + lane] = tot0 + s1 - c1; cur[64 + lane] = tot0 + s1 - c1;
    }
    __syncthreads();

    // exp + sorted scatter from the stash (no re-read)
    for (int k = 0; k < nk; ++k) {
        unsigned e = er[k];
        if ((e >> 23) != half) continue;
        int d  = e & 0xFFFFu;
        int ln = (e >> 16) & 127;
        float sc = ssL[ln] + s_dst[d];
        float lr = sc > 0.f ? sc : SLOPE * sc;
        float ev = __expf(lr);
        int pos = atomicAdd(&cur[ln], 1);
        pairs[pos] = make_uint2((unsigned)d, __float_as_uint(ev));
    }
    __syncthreads();

    const int e16 = lane >> 4;                    // quarter: edge offset
    const int c16 = lane & 15;                    // 4-dim group (uint2)

    #pragma unroll 1
    for (int t = 0; t < 16; ++t) {                // wave's 16 nodes
        const int ln  = wid * 16 + t;
        const int beg = ofs[ln];
        const int len = cntL[ln];

        float a0 = 0.f, a1 = 0.f, a2 = 0.f, a3 = 0.f, es = 0.f;
        int j = 0;
        for (; j + 16 <= len; j += 16) {          // 16 edges: 4 per quarter
            uint2 pA = pairs[beg + j + 0  + e16];
            uint2 pB = pairs[beg + j + 4  + e16];
            uint2 pC = pairs[beg + j + 8  + e16];
            uint2 pD = pairs[beg + j + 12 + e16];
            uint2 gA = nbufq[pA.x * 16 + c16];
            uint2 gB = nbufq[pB.x * 16 + c16];
            uint2 gC = nbufq[pC.x * 16 + c16];
            uint2 gD = nbufq[pD.x * 16 + c16];
            float fA = __uint_as_float(pA.y), fB = __uint_as_float(pB.y);
            float fC = __uint_as_float(pC.y), fD = __uint_as_float(pD.y);
            es += fA + fB + fC + fD;
            a0 = fmaf(fA, __uint_as_float(gA.x << 16), a0);
            a1 = fmaf(fA, __uint_as_float(gA.x & 0xFFFF0000u), a1);
            a2 = fmaf(fA, __uint_as_float(gA.y << 16), a2);
            a3 = fmaf(fA, __uint_as_float(gA.y & 0xFFFF0000u), a3);
            a0 = fmaf(fB, __uint_as_float(gB.x << 16), a0);
            a1 = fmaf(fB, __uint_as_float(gB.x & 0xFFFF0000u), a1);
            a2 = fmaf(fB, __uint_as_float(gB.y << 16), a2);
            a3 = fmaf(fB, __uint_as_float(gB.y & 0xFFFF0000u), a3);
            a0 = fmaf(fC, __uint_as_float(gC.x << 16), a0);
            a1 = fmaf(fC, __uint_as_float(gC.x & 0xFFFF0000u), a1);
            a2 = fmaf(fC, __uint_as_float(gC.y << 16), a2);
            a3 = fmaf(fC, __uint_as_float(gC.y & 0xFFFF0000u), a3);
            a0 = fmaf(fD, __uint_as_float(gD.x << 16), a0);
            a1 = fmaf(fD, __uint_as_float(gD.x & 0xFFFF0000u), a1);
            a2 = fmaf(fD, __uint_as_float(gD.y << 16), a2);
            a3 = fmaf(fD, __uint_as_float(gD.y & 0xFFFF0000u), a3);
        }
        for (; j < len; j += 4) {                 // tail: clamp + mask
            int idx = j + e16;
            uint2 p = pairs[beg + min(idx, len - 1)];
            float f = (idx < len) ? __uint_as_float(p.y) : 0.f;
            uint2 g = nbufq[p.x * 16 + c16];
            es += f;
            a0 = fmaf(f, __uint_as_float(g.x << 16), a0);
            a1 = fmaf(f, __uint_as_float(g.x & 0xFFFF0000u), a1);
            a2 = fmaf(f, __uint_as_float(g.y << 16), a2);
            a3 = fmaf(f, __uint_as_float(g.y & 0xFFFF0000u), a3);
        }
        es += __shfl_xor(es, 16, 64); es += __shfl_xor(es, 32, 64);
        a0 += __shfl_xor(a0, 16, 64); a0 += __shfl_xor(a0, 32, 64);
        a1 += __shfl_xor(a1, 16, 64); a1 += __shfl_xor(a1, 32, 64);
        a2 += __shfl_xor(a2, 16, 64); a2 += __shfl_xor(a2, 32, 64);
        a3 += __shfl_xor(a3, 16, 64); a3 += __shfl_xor(a3, 32, 64);
        const int n = n0 + ln;
        if (e16 == 0 && n < NN) {
            float inv = 1.f / (es + 1e-12f);
            float4 o = make_float4(a0 * inv, a1 * inv, a2 * inv, a3 * inv);
            *(float4*)&out[(size_t)n * OUTD + c16 * 4] = o;
        }
    }
}

// ---------------------------------------------------------------------------
extern "C" void kernel_launch(void* const* d_in, const int* in_sizes, int n_in,
                              void* d_out, int out_size, void* d_ws, size_t ws_size,
                              hipStream_t stream) {
    const float* x  = (const float*)d_in[0];
    const int*   ei = (const int*)d_in[1];    // (2,E): [0..E)=src, [E..2E)=dst
    const float* W  = (const float*)d_in[2];
    const float* b  = (const float*)d_in[3];
    const float* a  = (const float*)d_in[4];
    float* out = (float*)d_out;

    // workspace layout (~14 MB)
    ushort*   nbuf2 = (ushort*)d_ws;                      // N*64 bf16 = 6.4 MB
    float*    s_src = (float*)(nbuf2 + (size_t)NN * OUTD);// N
    float*    s_dst = s_src + NN;                         // N
    int*      gcur1 = (int*)(s_dst + NN);                 // NC*16
    unsigned* ebuf1 = (unsigned*)(gcur1 + NC * 16);       // NC*CAP1 = 6.9 MB

    hipMemsetAsync(gcur1, 0, NC * 16 * sizeof(int), stream);
    fused_lincoarse_kernel<<<NBLK1 + NLIN, 256, 0, stream>>>(
        x, W, b, a, ei, gcur1, ebuf1, nbuf2, s_src, s_dst);
    aggregate_kernel<<<NAGG, 512, 0, stream>>>(ebuf1, gcur1, nbuf2, s_src, s_dst, out);
}